// Round 1
// baseline (317.504 us; speedup 1.0000x reference)
//
#include <hip/hip_runtime.h>
#include <hip/hip_bf16.h>

// EventSequenceEncoder: embed -> QKV gemm -> attention -> Wout(+res) -> LN ->
// FF1(relu) -> FF2(+res) -> LN -> mean-pool.  attn_tokens == 1/L analytically.
// All big GEMMs in bf16 MFMA (16x16x32), f32 accumulate, m97-style 128x128 tile.

#define Dm 1024
#define Hh 16
#define Bb 8
#define Ll 1024
#define Mm 8192
#define LNEPS 1e-5f

typedef __attribute__((ext_vector_type(8))) short s16x8;
typedef __attribute__((ext_vector_type(4))) short s16x4;
typedef __attribute__((ext_vector_type(4))) float f32x4;

using bf16 = __hip_bfloat16;

__device__ __forceinline__ short f2bs(float f) {
  return __builtin_bit_cast(short, __float2bfloat16(f));
}

__device__ __forceinline__ void gload16(const void* g, void* l) {
  __builtin_amdgcn_global_load_lds(
      (__attribute__((address_space(1))) void*)g,
      (__attribute__((address_space(3))) void*)l, 16, 0, 0);
}

// ---------------- weight f32 -> bf16 ----------------
__global__ __launch_bounds__(256) void k_f2b(const float* __restrict__ x, bf16* __restrict__ y)
{
  const size_t i = ((size_t)blockIdx.x * 256 + threadIdx.x) * 4;
  const float4 v = *(const float4*)&x[i];
  s16x4 o;
  o[0] = f2bs(v.x); o[1] = f2bs(v.y); o[2] = f2bs(v.z); o[3] = f2bs(v.w);
  *(s16x4*)&y[i] = o;
}

// ---------------- fused embedding ----------------
__global__ __launch_bounds__(256) void k_embed(
    const int* __restrict__ tids, const float* __restrict__ vals, const float* __restrict__ dels,
    const float* __restrict__ temb, const float* __restrict__ Wv, const float* __restrict__ bv,
    const float* __restrict__ Wt, const float* __restrict__ bt,
    float* __restrict__ hf, bf16* __restrict__ hb)
{
  const int row = blockIdx.x;
  const int ty = tids[row];
  const float v = vals[row], dl = dels[row];
  const int d0 = threadIdx.x * 4;
  const float4 e  = *(const float4*)&temb[(size_t)ty * Dm + d0];
  const float4 wv = *(const float4*)&Wv[d0];
  const float4 c1 = *(const float4*)&bv[d0];
  const float4 wt = *(const float4*)&Wt[d0];
  const float4 c2 = *(const float4*)&bt[d0];
  float4 h;
  h.x = e.x + v * wv.x + c1.x + dl * wt.x + c2.x;
  h.y = e.y + v * wv.y + c1.y + dl * wt.y + c2.y;
  h.z = e.z + v * wv.z + c1.z + dl * wt.z + c2.z;
  h.w = e.w + v * wv.w + c1.w + dl * wt.w + c2.w;
  *(float4*)&hf[(size_t)row * Dm + d0] = h;
  s16x4 o;
  o[0] = f2bs(h.x); o[1] = f2bs(h.y); o[2] = f2bs(h.z); o[3] = f2bs(h.w);
  *(s16x4*)((short*)hb + (size_t)row * Dm + d0) = o;
}

// ---------------- GEMM: out = A[M,K] @ Bt[N,K]^T + bias (+res) ----------------
// m97 structure: 128x128 tile, BK=32, 4 waves (2x2), global_load_lds width 16.
template<bool RELU, bool OUTF, bool OUTB, bool RES>
__global__ __launch_bounds__(256) void k_gemm_bt(
    const bf16* __restrict__ A, const bf16* __restrict__ Bt,
    const float* __restrict__ bias, const float* __restrict__ res,
    float* __restrict__ outF, bf16* __restrict__ outB, const int N, const int K)
{
  __shared__ __attribute__((aligned(16))) short lA[4096];
  __shared__ __attribute__((aligned(16))) short lB[4096];
  const int tid = threadIdx.x, lane = tid & 63, wave = tid >> 6;
  const int wr = wave >> 1, wc = wave & 1;
  const int l15 = lane & 15, lg = lane >> 4;
  const size_t bm = blockIdx.x, bn = blockIdx.y;
  f32x4 acc[4][4] = {};
  const int srow = tid >> 2, scol = (tid & 3) << 3;
  const bf16* ga = A  + (bm * 128 + srow) * (size_t)K + scol;
  const bf16* gb = Bt + (bn * 128 + srow) * (size_t)K + scol;
  for (int k0 = 0; k0 < K; k0 += 32) {
    gload16(ga + k0,                  &lA[tid * 8]);
    gload16(ga + k0 + (size_t)64 * K, &lA[2048 + tid * 8]);
    gload16(gb + k0,                  &lB[tid * 8]);
    gload16(gb + k0 + (size_t)64 * K, &lB[2048 + tid * 8]);
    __syncthreads();
    s16x8 fa[4], fb[4];
#pragma unroll
    for (int m = 0; m < 4; ++m)
      fa[m] = *(const s16x8*)&lA[(wr * 64 + m * 16 + l15) * 32 + lg * 8];
#pragma unroll
    for (int n = 0; n < 4; ++n)
      fb[n] = *(const s16x8*)&lB[(wc * 64 + n * 16 + l15) * 32 + lg * 8];
#pragma unroll
    for (int m = 0; m < 4; ++m)
#pragma unroll
      for (int n = 0; n < 4; ++n)
        acc[m][n] = __builtin_amdgcn_mfma_f32_16x16x32_bf16(fa[m], fb[n], acc[m][n], 0, 0, 0);
    __syncthreads();
  }
#pragma unroll
  for (int n = 0; n < 4; ++n) {
    const int col = (int)bn * 128 + wc * 64 + n * 16 + l15;
    const float bc = bias[col];
#pragma unroll
    for (int m = 0; m < 4; ++m) {
#pragma unroll
      for (int i = 0; i < 4; ++i) {
        const size_t row = bm * 128 + wr * 64 + m * 16 + lg * 4 + i;
        float v = acc[m][n][i] + bc;
        if constexpr (RES)  v += res[row * N + col];
        if constexpr (RELU) v = fmaxf(v, 0.f);
        if constexpr (OUTF) outF[row * N + col] = v;
        if constexpr (OUTB) outB[row * N + col] = __float2bfloat16(v);
      }
    }
  }
}

// ---------------- V transpose: vt[b,h][dh][l] = v[b,l,h,dh] ----------------
__global__ __launch_bounds__(256) void k_vt(const bf16* __restrict__ qkv, bf16* __restrict__ vt)
{
  const int bh = blockIdx.x, lc = blockIdx.y;
  const int b = bh >> 4, h = bh & 15;
  __shared__ short tile[64][72];
  const int r = threadIdx.x >> 2;
  const int c0 = (threadIdx.x & 3) << 4;
  const short* src = (const short*)qkv + ((size_t)(b * Ll + lc * 64 + r)) * 3072 + 2048 + h * 64 + c0;
  const s16x8 x0 = *(const s16x8*)src;
  const s16x8 x1 = *(const s16x8*)(src + 8);
#pragma unroll
  for (int j = 0; j < 8; ++j) { tile[r][c0 + j] = x0[j]; tile[r][c0 + 8 + j] = x1[j]; }
  __syncthreads();
  s16x8 y0, y1;
#pragma unroll
  for (int j = 0; j < 8; ++j) { y0[j] = tile[c0 + j][r]; y1[j] = tile[c0 + 8 + j][r]; }
  short* dst = (short*)vt + ((size_t)(bh * 64 + r)) * Ll + lc * 64 + c0;
  *(s16x8*)dst = y0;
  *(s16x8*)(dst + 8) = y1;
}

// ---------------- attention (no-max softmax, single pass) ----------------
// block = one (b,h) x 64 q-rows; 4 waves x 16 rows. KV chunks of 64.
// LDS tiles 64x64 bf16 (128B rows) -> XOR-swizzle slot^(row&7); staged via
// global_load_lds with pre-swizzled global source (linear dest).
__global__ __launch_bounds__(256) void k_attn(
    const bf16* __restrict__ qkv, const bf16* __restrict__ vt, bf16* __restrict__ attnb)
{
  const int bh = blockIdx.x;
  const int qb = blockIdx.y;
  const int b = bh >> 4, h = bh & 15;
  __shared__ __attribute__((aligned(16))) short lQ[4096];
  __shared__ __attribute__((aligned(16))) short lK[4096];
  __shared__ __attribute__((aligned(16))) short lV[4096];
  __shared__ __attribute__((aligned(16))) short lP[4096];
  const int tid = threadIdx.x, lane = tid & 63, wave = tid >> 6;
  const int l15 = lane & 15, lg = lane >> 4;

  {
    const int r = tid >> 3;
    const int sw = (tid & 7) ^ (r & 7);
    const bf16* gq = qkv + ((size_t)(b * Ll + qb * 64 + r)) * 3072 + h * 64 + sw * 8;
    gload16(gq,                    &lQ[tid * 8]);
    gload16(gq + (size_t)32 * 3072, &lQ[2048 + tid * 8]);
  }

  f32x4 o[4] = {};
  float rs[4] = {0.f, 0.f, 0.f, 0.f};

  for (int mc = 0; mc < 16; ++mc) {
    __syncthreads();
    {
      const int r = tid >> 3;
      const int sw = (tid & 7) ^ (r & 7);
      const bf16* gk = qkv + ((size_t)(b * Ll + mc * 64 + r)) * 3072 + 1024 + h * 64 + sw * 8;
      gload16(gk,                     &lK[tid * 8]);
      gload16(gk + (size_t)32 * 3072, &lK[2048 + tid * 8]);
      const bf16* gv = vt + ((size_t)(bh * 64 + r)) * Ll + mc * 64 + sw * 8;
      gload16(gv,                   &lV[tid * 8]);
      gload16(gv + (size_t)32 * Ll, &lV[2048 + tid * 8]);
    }
    __syncthreads();

    // S = Q K^T for rows [wave*16, wave*16+16)
    s16x8 aq[2];
#pragma unroll
    for (int ks = 0; ks < 2; ++ks) {
      const int row = wave * 16 + l15;
      const int slot = (ks * 4 + lg) ^ (row & 7);
      aq[ks] = *(const s16x8*)&lQ[row * 64 + slot * 8];
    }
    f32x4 s4[4];
#pragma unroll
    for (int n = 0; n < 4; ++n) {
      f32x4 acc = {};
#pragma unroll
      for (int ks = 0; ks < 2; ++ks) {
        const int kr = n * 16 + l15;
        const int slot = (ks * 4 + lg) ^ (kr & 7);
        const s16x8 bk = *(const s16x8*)&lK[kr * 64 + slot * 8];
        acc = __builtin_amdgcn_mfma_f32_16x16x32_bf16(aq[ks], bk, acc, 0, 0, 0);
      }
      s4[n] = acc;
    }
    float part[4] = {0.f, 0.f, 0.f, 0.f};
#pragma unroll
    for (int n = 0; n < 4; ++n) {
#pragma unroll
      for (int i = 0; i < 4; ++i) {
        const float p = __expf(s4[n][i] * 0.125f);
        part[i] += p;
        const int pr = wave * 16 + lg * 4 + i;
        const int pc = n * 16 + l15;
        lP[pr * 64 + (((pc >> 3) ^ (pr & 7)) << 3) + (pc & 7)] = f2bs(p);
      }
    }
#pragma unroll
    for (int i = 0; i < 4; ++i) {
      part[i] += __shfl_xor(part[i], 1);
      part[i] += __shfl_xor(part[i], 2);
      part[i] += __shfl_xor(part[i], 4);
      part[i] += __shfl_xor(part[i], 8);
      rs[i] += part[i];
    }
    __syncthreads();

    // O += P V
#pragma unroll
    for (int ks = 0; ks < 2; ++ks) {
      const int pr = wave * 16 + l15;
      const int slot = (ks * 4 + lg) ^ (pr & 7);
      const s16x8 ap = *(const s16x8*)&lP[pr * 64 + slot * 8];
#pragma unroll
      for (int n = 0; n < 4; ++n) {
        const int vr = n * 16 + l15;
        const int vslot = (ks * 4 + lg) ^ (vr & 7);
        const s16x8 bv8 = *(const s16x8*)&lV[vr * 64 + vslot * 8];
        o[n] = __builtin_amdgcn_mfma_f32_16x16x32_bf16(ap, bv8, o[n], 0, 0, 0);
      }
    }
  }

#pragma unroll
  for (int n = 0; n < 4; ++n) {
#pragma unroll
    for (int i = 0; i < 4; ++i) {
      const int r = wave * 16 + lg * 4 + i;
      const int dh = n * 16 + l15;
      const float val = o[n][i] / rs[i];
      attnb[((size_t)(b * Ll + qb * 64 + r)) * Dm + h * 64 + dh] = __float2bfloat16(val);
    }
  }
}

// ---------------- LayerNorm (one row per block) ----------------
template<bool WB>
__global__ __launch_bounds__(256) void k_ln(const float* __restrict__ x,
    const float* __restrict__ gamma, const float* __restrict__ beta,
    float* __restrict__ yf, bf16* __restrict__ yb)
{
  const size_t row = blockIdx.x;
  const int d0 = threadIdx.x * 4;
  const float4 xv = *(const float4*)&x[row * Dm + d0];
  float s  = xv.x + xv.y + xv.z + xv.w;
  float ss = xv.x * xv.x + xv.y * xv.y + xv.z * xv.z + xv.w * xv.w;
#pragma unroll
  for (int m = 1; m < 64; m <<= 1) { s += __shfl_xor(s, m); ss += __shfl_xor(ss, m); }
  __shared__ float red[8];
  const int wv = threadIdx.x >> 6;
  if ((threadIdx.x & 63) == 0) { red[wv] = s; red[4 + wv] = ss; }
  __syncthreads();
  s  = red[0] + red[1] + red[2] + red[3];
  ss = red[4] + red[5] + red[6] + red[7];
  const float mu = s * (1.f / Dm);
  const float rstd = rsqrtf(ss * (1.f / Dm) - mu * mu + LNEPS);
  const float4 g  = *(const float4*)&gamma[d0];
  const float4 be = *(const float4*)&beta[d0];
  float4 y;
  y.x = (xv.x - mu) * rstd * g.x + be.x;
  y.y = (xv.y - mu) * rstd * g.y + be.y;
  y.z = (xv.z - mu) * rstd * g.z + be.z;
  y.w = (xv.w - mu) * rstd * g.w + be.w;
  *(float4*)&yf[row * Dm + d0] = y;
  if constexpr (WB) {
    s16x4 o;
    o[0] = f2bs(y.x); o[1] = f2bs(y.y); o[2] = f2bs(y.z); o[3] = f2bs(y.w);
    *(s16x4*)((short*)yb + row * Dm + d0) = o;
  }
}

// ---------------- mean pool ----------------
__global__ __launch_bounds__(256) void k_pool_part(const float* __restrict__ h3, float* __restrict__ part)
{
  const int b = blockIdx.x, lcn = blockIdx.y, dz = blockIdx.z;
  const int d = dz * 256 + threadIdx.x;
  float s = 0.f;
#pragma unroll 4
  for (int l = 0; l < 64; ++l)
    s += h3[((size_t)(b * Ll + lcn * 64 + l)) * Dm + d];
  part[((size_t)(b * 16 + lcn)) * Dm + d] = s;
}

__global__ __launch_bounds__(256) void k_pool_fin(const float* __restrict__ part, float* __restrict__ out)
{
  const int b = blockIdx.x;
  const int d = blockIdx.y * 256 + threadIdx.x;
  float s = 0.f;
#pragma unroll
  for (int c = 0; c < 16; ++c) s += part[((size_t)(b * 16 + c)) * Dm + d];
  out[b * Dm + d] = s * (1.f / Ll);
  out[(size_t)Mm + b * Dm + d] = 1.f / Ll;  // attn_tokens == 1/L analytically
}

extern "C" void kernel_launch(void* const* d_in, const int* in_sizes, int n_in,
                              void* d_out, int out_size, void* d_ws, size_t ws_size,
                              hipStream_t stream) {
  const int*   tids  = (const int*)  d_in[0];
  const float* vals  = (const float*)d_in[1];
  const float* dels  = (const float*)d_in[2];
  const float* temb  = (const float*)d_in[3];
  const float* Wv    = (const float*)d_in[4];
  const float* bv    = (const float*)d_in[5];
  const float* Wt    = (const float*)d_in[6];
  const float* bt    = (const float*)d_in[7];
  const float* Win   = (const float*)d_in[8];
  const float* bin   = (const float*)d_in[9];
  const float* Wout  = (const float*)d_in[10];
  const float* bout  = (const float*)d_in[11];
  const float* W1    = (const float*)d_in[12];
  const float* b1    = (const float*)d_in[13];
  const float* W2    = (const float*)d_in[14];
  const float* b2    = (const float*)d_in[15];
  const float* gamma = (const float*)d_in[16];
  const float* beta  = (const float*)d_in[17];
  float* out = (float*)d_out;

  char* w = (char*)d_ws;
  const size_t MB = 1ull << 20;
  // region plan (peak 141.5 MiB, regions reused across phases):
  float* hf    = (float*)(w + 0);         // [0,32)   h f32
  bf16*  hb    = (bf16*) (w + 32 * MB);   // [32,48)  h bf16
  bf16*  qkv   = (bf16*) (w + 48 * MB);   // [48,96)  qkv bf16
  bf16*  vtb   = (bf16*) (w + 96 * MB);   // [96,112) v^T bf16
  bf16*  attnb = (bf16*) (w + 112 * MB);  // [112,128) attn bf16
  float* x1    = (float*)(w + 48 * MB);   // [48,80)  h+attn_out (qkv dead)
  float* h2f   = (float*)(w + 80 * MB);   // [80,112) h2 f32 (qkv tail+vt dead)
  bf16*  h2b   = (bf16*) (w + 32 * MB);   // [32,48)  h2 bf16 (hb dead)
  bf16*  ff1   = (bf16*) (w + 112 * MB);  // [112,128) relu(ff1) (attnb dead)
  float* x2    = (float*)(w + 0);         // [0,32)   h2+ff2 (hf dead)
  float* h3    = (float*)(w + 48 * MB);   // [48,80)  h3 (x1 dead)
  bf16*  WinB  = (bf16*) (w + 129 * MB);  // 6MB
  bf16*  WoutB = (bf16*) (w + 135 * MB);  // 2MB
  bf16*  W1B   = (bf16*) (w + 137 * MB);  // 2MB
  bf16*  W2B   = (bf16*) (w + 139 * MB);  // 2MB
  float* part  = (float*)(w + 141 * MB);  // 512KB

  k_f2b<<<3072, 256, 0, stream>>>(Win,  WinB);
  k_f2b<<<1024, 256, 0, stream>>>(Wout, WoutB);
  k_f2b<<<1024, 256, 0, stream>>>(W1,   W1B);
  k_f2b<<<1024, 256, 0, stream>>>(W2,   W2B);

  k_embed<<<Mm, 256, 0, stream>>>(tids, vals, dels, temb, Wv, bv, Wt, bt, hf, hb);

  k_gemm_bt<false, false, true, false><<<dim3(64, 24), 256, 0, stream>>>(
      hb, WinB, bin, nullptr, nullptr, qkv, 3072, 1024);

  k_vt<<<dim3(128, 16), 256, 0, stream>>>(qkv, vtb);
  k_attn<<<dim3(128, 16), 256, 0, stream>>>(qkv, vtb, attnb);

  k_gemm_bt<false, true, false, true><<<dim3(64, 8), 256, 0, stream>>>(
      attnb, WoutB, bout, hf, x1, nullptr, 1024, 1024);

  k_ln<true><<<Mm, 256, 0, stream>>>(x1, gamma, beta, h2f, h2b);

  k_gemm_bt<true, false, true, false><<<dim3(64, 8), 256, 0, stream>>>(
      h2b, W1B, b1, nullptr, nullptr, ff1, 1024, 1024);

  k_gemm_bt<false, true, false, true><<<dim3(64, 8), 256, 0, stream>>>(
      ff1, W2B, b2, h2f, x2, nullptr, 1024, 1024);

  k_ln<false><<<Mm, 256, 0, stream>>>(x2, gamma, beta, h3, nullptr);

  k_pool_part<<<dim3(8, 16, 4), 256, 0, stream>>>(h3, part);
  k_pool_fin<<<dim3(8, 4), 256, 0, stream>>>(part, out);
}

// Round 2
// 273.239 us; speedup vs baseline: 1.1620x; 1.1620x over previous
//
#include <hip/hip_runtime.h>
#include <hip/hip_bf16.h>

// EventSequenceEncoder: embed -> QKV gemm -> attention -> Wout(+res) -> LN ->
// FF1(relu) -> FF2(+res) -> LN -> mean-pool.  attn_tokens == 1/L analytically.
// R1: attention rewritten: swapped QK^T (S^T = K x Q) so P-k is lane-local ->
// packed b32 P writes, wave-private lP (no 3rd barrier), Q in registers,
// QBLK=128 (32 MFMA per chunk per wave vs 16), setprio around MFMA.

#define Dm 1024
#define Hh 16
#define Bb 8
#define Ll 1024
#define Mm 8192
#define LNEPS 1e-5f

typedef __attribute__((ext_vector_type(8))) short s16x8;
typedef __attribute__((ext_vector_type(4))) short s16x4;
typedef __attribute__((ext_vector_type(4))) float f32x4;

using bf16 = __hip_bfloat16;

__device__ __forceinline__ short f2bs(float f) {
  return __builtin_bit_cast(short, __float2bfloat16(f));
}

__device__ __forceinline__ unsigned cvtpk(float lo, float hi) {
  unsigned r;
  asm("v_cvt_pk_bf16_f32 %0, %1, %2" : "=v"(r) : "v"(lo), "v"(hi));
  return r;
}

__device__ __forceinline__ void gload16(const void* g, void* l) {
  __builtin_amdgcn_global_load_lds(
      (__attribute__((address_space(1))) void*)g,
      (__attribute__((address_space(3))) void*)l, 16, 0, 0);
}

// ---------------- weight f32 -> bf16 ----------------
__global__ __launch_bounds__(256) void k_f2b(const float* __restrict__ x, bf16* __restrict__ y)
{
  const size_t i = ((size_t)blockIdx.x * 256 + threadIdx.x) * 4;
  const float4 v = *(const float4*)&x[i];
  s16x4 o;
  o[0] = f2bs(v.x); o[1] = f2bs(v.y); o[2] = f2bs(v.z); o[3] = f2bs(v.w);
  *(s16x4*)&y[i] = o;
}

// ---------------- fused embedding ----------------
__global__ __launch_bounds__(256) void k_embed(
    const int* __restrict__ tids, const float* __restrict__ vals, const float* __restrict__ dels,
    const float* __restrict__ temb, const float* __restrict__ Wv, const float* __restrict__ bv,
    const float* __restrict__ Wt, const float* __restrict__ bt,
    float* __restrict__ hf, bf16* __restrict__ hb)
{
  const int row = blockIdx.x;
  const int ty = tids[row];
  const float v = vals[row], dl = dels[row];
  const int d0 = threadIdx.x * 4;
  const float4 e  = *(const float4*)&temb[(size_t)ty * Dm + d0];
  const float4 wv = *(const float4*)&Wv[d0];
  const float4 c1 = *(const float4*)&bv[d0];
  const float4 wt = *(const float4*)&Wt[d0];
  const float4 c2 = *(const float4*)&bt[d0];
  float4 h;
  h.x = e.x + v * wv.x + c1.x + dl * wt.x + c2.x;
  h.y = e.y + v * wv.y + c1.y + dl * wt.y + c2.y;
  h.z = e.z + v * wv.z + c1.z + dl * wt.z + c2.z;
  h.w = e.w + v * wv.w + c1.w + dl * wt.w + c2.w;
  *(float4*)&hf[(size_t)row * Dm + d0] = h;
  s16x4 o;
  o[0] = f2bs(h.x); o[1] = f2bs(h.y); o[2] = f2bs(h.z); o[3] = f2bs(h.w);
  *(s16x4*)((short*)hb + (size_t)row * Dm + d0) = o;
}

// ---------------- GEMM: out = A[M,K] @ Bt[N,K]^T + bias (+res) ----------------
template<bool RELU, bool OUTF, bool OUTB, bool RES>
__global__ __launch_bounds__(256) void k_gemm_bt(
    const bf16* __restrict__ A, const bf16* __restrict__ Bt,
    const float* __restrict__ bias, const float* __restrict__ res,
    float* __restrict__ outF, bf16* __restrict__ outB, const int N, const int K)
{
  __shared__ __attribute__((aligned(16))) short lA[4096];
  __shared__ __attribute__((aligned(16))) short lB[4096];
  const int tid = threadIdx.x, lane = tid & 63, wave = tid >> 6;
  const int wr = wave >> 1, wc = wave & 1;
  const int l15 = lane & 15, lg = lane >> 4;
  const size_t bm = blockIdx.x, bn = blockIdx.y;
  f32x4 acc[4][4] = {};
  const int srow = tid >> 2, scol = (tid & 3) << 3;
  const bf16* ga = A  + (bm * 128 + srow) * (size_t)K + scol;
  const bf16* gb = Bt + (bn * 128 + srow) * (size_t)K + scol;
  for (int k0 = 0; k0 < K; k0 += 32) {
    gload16(ga + k0,                  &lA[tid * 8]);
    gload16(ga + k0 + (size_t)64 * K, &lA[2048 + tid * 8]);
    gload16(gb + k0,                  &lB[tid * 8]);
    gload16(gb + k0 + (size_t)64 * K, &lB[2048 + tid * 8]);
    __syncthreads();
    s16x8 fa[4], fb[4];
#pragma unroll
    for (int m = 0; m < 4; ++m)
      fa[m] = *(const s16x8*)&lA[(wr * 64 + m * 16 + l15) * 32 + lg * 8];
#pragma unroll
    for (int n = 0; n < 4; ++n)
      fb[n] = *(const s16x8*)&lB[(wc * 64 + n * 16 + l15) * 32 + lg * 8];
    __builtin_amdgcn_s_setprio(1);
#pragma unroll
    for (int m = 0; m < 4; ++m)
#pragma unroll
      for (int n = 0; n < 4; ++n)
        acc[m][n] = __builtin_amdgcn_mfma_f32_16x16x32_bf16(fa[m], fb[n], acc[m][n], 0, 0, 0);
    __builtin_amdgcn_s_setprio(0);
    __syncthreads();
  }
#pragma unroll
  for (int n = 0; n < 4; ++n) {
    const int col = (int)bn * 128 + wc * 64 + n * 16 + l15;
    const float bc = bias[col];
#pragma unroll
    for (int m = 0; m < 4; ++m) {
#pragma unroll
      for (int i = 0; i < 4; ++i) {
        const size_t row = bm * 128 + wr * 64 + m * 16 + lg * 4 + i;
        float v = acc[m][n][i] + bc;
        if constexpr (RES)  v += res[row * N + col];
        if constexpr (RELU) v = fmaxf(v, 0.f);
        if constexpr (OUTF) outF[row * N + col] = v;
        if constexpr (OUTB) outB[row * N + col] = __float2bfloat16(v);
      }
    }
  }
}

// ---------------- V transpose: vt[b,h][dh][l] = v[b,l,h,dh] ----------------
__global__ __launch_bounds__(256) void k_vt(const bf16* __restrict__ qkv, bf16* __restrict__ vt)
{
  const int bh = blockIdx.x, lc = blockIdx.y;
  const int b = bh >> 4, h = bh & 15;
  __shared__ short tile[64][72];
  const int r = threadIdx.x >> 2;
  const int c0 = (threadIdx.x & 3) << 4;
  const short* src = (const short*)qkv + ((size_t)(b * Ll + lc * 64 + r)) * 3072 + 2048 + h * 64 + c0;
  const s16x8 x0 = *(const s16x8*)src;
  const s16x8 x1 = *(const s16x8*)(src + 8);
#pragma unroll
  for (int j = 0; j < 8; ++j) { tile[r][c0 + j] = x0[j]; tile[r][c0 + 8 + j] = x1[j]; }
  __syncthreads();
  s16x8 y0, y1;
#pragma unroll
  for (int j = 0; j < 8; ++j) { y0[j] = tile[c0 + j][r]; y1[j] = tile[c0 + 8 + j][r]; }
  short* dst = (short*)vt + ((size_t)(bh * 64 + r)) * Ll + lc * 64 + c0;
  *(s16x8*)dst = y0;
  *(s16x8*)(dst + 8) = y1;
}

// ---------------- attention v2: swapped QK^T, wave-private P, QBLK=128 ----------------
// grid (128 bh, 8 qb); 4 waves x 32 q-rows. KV chunks of 64.
// S^T = mfma(A=K, B=Q): lane holds P^T[k = n*16+lg*4+i][q = l15] -> k lane-local:
// rowsum = local adds (+2 shfl at end), P packed via v_cvt_pk_bf16_f32,
// 8 ds_write_b32 per mq per chunk into wave-private lP (no barrier).
__global__ __launch_bounds__(256) void k_attn(
    const bf16* __restrict__ qkv, const bf16* __restrict__ vt, bf16* __restrict__ attnb)
{
  const int bh = blockIdx.x;
  const int qb = blockIdx.y;
  const int b = bh >> 4, h = bh & 15;
  __shared__ __attribute__((aligned(16))) short lK[4096];   // [64][64] swz
  __shared__ __attribute__((aligned(16))) short lV[4096];   // [64][64] swz (rows = dh)
  __shared__ __attribute__((aligned(16))) short lP[8192];   // [128][64] swz, wave-private rows
  const int tid = threadIdx.x, lane = tid & 63, wave = tid >> 6;
  const int l15 = lane & 15, lg = lane >> 4;
  const int qrow = wave * 32;          // wave's q-row base within block
  const int l7 = l15 & 7;

  // Q B-fragments in registers: lane holds Q[qb*128+qrow+mq*16+l15][h*64+ks*32+lg*8..+7]
  s16x8 qf[2][2];
#pragma unroll
  for (int mq = 0; mq < 2; ++mq)
#pragma unroll
    for (int ks = 0; ks < 2; ++ks)
      qf[mq][ks] = *(const s16x8*)((const short*)qkv +
          ((size_t)(b * Ll + qb * 128 + qrow + mq * 16 + l15)) * 3072 + h * 64 + ks * 32 + lg * 8);

  f32x4 o[2][4] = {};
  float rs[2] = {0.f, 0.f};

  const int sr = tid >> 3;             // staging row 0..31
  const int sc = tid & 7;
  const int swz = sc ^ (sr & 7);

  for (int mc = 0; mc < 16; ++mc) {
    __syncthreads();
    {
      const bf16* gk = qkv + ((size_t)(b * Ll + mc * 64 + sr)) * 3072 + 1024 + h * 64 + swz * 8;
      gload16(gk,                     &lK[tid * 8]);
      gload16(gk + (size_t)32 * 3072, &lK[2048 + tid * 8]);
      const bf16* gv = vt + ((size_t)(bh * 64 + sr)) * Ll + mc * 64 + swz * 8;
      gload16(gv,                   &lV[tid * 8]);
      gload16(gv + (size_t)32 * Ll, &lV[2048 + tid * 8]);
    }
    __syncthreads();

    // S^T = K x Q : st[mq][n][i] = S^T[n*16+lg*4+i][qrow+mq*16+l15]
    f32x4 st[2][4] = {};
    __builtin_amdgcn_s_setprio(1);
#pragma unroll
    for (int ks = 0; ks < 2; ++ks) {
#pragma unroll
      for (int n = 0; n < 4; ++n) {
        const int kr = n * 16 + l15;
        const s16x8 kf = *(const s16x8*)&lK[kr * 64 + (((ks * 4 + lg) ^ l7) << 3)];
        st[0][n] = __builtin_amdgcn_mfma_f32_16x16x32_bf16(kf, qf[0][ks], st[0][n], 0, 0, 0);
        st[1][n] = __builtin_amdgcn_mfma_f32_16x16x32_bf16(kf, qf[1][ks], st[1][n], 0, 0, 0);
      }
    }
    __builtin_amdgcn_s_setprio(0);

    // exp + pack + wave-private LDS write + local rowsum
#pragma unroll
    for (int mq = 0; mq < 2; ++mq) {
      const int qr = qrow + mq * 16 + l15;
      short* prow = &lP[qr * 64];
      float loc = 0.f;
#pragma unroll
      for (int n = 0; n < 4; ++n) {
        const float e0 = __expf(st[mq][n][0] * 0.125f);
        const float e1 = __expf(st[mq][n][1] * 0.125f);
        const float e2 = __expf(st[mq][n][2] * 0.125f);
        const float e3 = __expf(st[mq][n][3] * 0.125f);
        loc += (e0 + e1) + (e2 + e3);
        const unsigned c0 = cvtpk(e0, e1);
        const unsigned c1 = cvtpk(e2, e3);
        const int col0 = n * 16 + lg * 4;                       // k within chunk
        const int scol = ((((col0 >> 3) ^ (qr & 7)) << 3) | (col0 & 7));
        *(unsigned*)&prow[scol]     = c0;
        *(unsigned*)&prow[scol + 2] = c1;
      }
      rs[mq] += loc;
    }

    // O += P V  (P A-frags from wave-private lP; V B-frags from lV)
    __builtin_amdgcn_s_setprio(1);
#pragma unroll
    for (int ks = 0; ks < 2; ++ks) {
      s16x8 pa[2];
#pragma unroll
      for (int mq = 0; mq < 2; ++mq) {
        const int qr = qrow + mq * 16 + l15;
        pa[mq] = *(const s16x8*)&lP[qr * 64 + (((ks * 4 + lg) ^ (qr & 7)) << 3)];
      }
#pragma unroll
      for (int dn = 0; dn < 4; ++dn) {
        const int vr = dn * 16 + l15;
        const s16x8 vf = *(const s16x8*)&lV[vr * 64 + (((ks * 4 + lg) ^ l7) << 3)];
        o[0][dn] = __builtin_amdgcn_mfma_f32_16x16x32_bf16(pa[0], vf, o[0][dn], 0, 0, 0);
        o[1][dn] = __builtin_amdgcn_mfma_f32_16x16x32_bf16(pa[1], vf, o[1][dn], 0, 0, 0);
      }
    }
    __builtin_amdgcn_s_setprio(0);
  }

  // finish rowsums (across lg groups: lane bits 4,5) and store normalized O
#pragma unroll
  for (int mq = 0; mq < 2; ++mq) {
    rs[mq] += __shfl_xor(rs[mq], 16);
    rs[mq] += __shfl_xor(rs[mq], 32);
  }
#pragma unroll
  for (int mq = 0; mq < 2; ++mq) {
    float inv[4];
#pragma unroll
    for (int i = 0; i < 4; ++i)
      inv[i] = 1.f / __shfl(rs[mq], lg * 4 + i);
#pragma unroll
    for (int dn = 0; dn < 4; ++dn) {
#pragma unroll
      for (int i = 0; i < 4; ++i) {
        const int q = qb * 128 + qrow + mq * 16 + lg * 4 + i;
        attnb[((size_t)(b * Ll + q)) * Dm + h * 64 + dn * 16 + l15] =
            __float2bfloat16(o[mq][dn][i] * inv[i]);
      }
    }
  }
}

// ---------------- LayerNorm (one row per block) ----------------
template<bool WB>
__global__ __launch_bounds__(256) void k_ln(const float* __restrict__ x,
    const float* __restrict__ gamma, const float* __restrict__ beta,
    float* __restrict__ yf, bf16* __restrict__ yb)
{
  const size_t row = blockIdx.x;
  const int d0 = threadIdx.x * 4;
  const float4 xv = *(const float4*)&x[row * Dm + d0];
  float s  = xv.x + xv.y + xv.z + xv.w;
  float ss = xv.x * xv.x + xv.y * xv.y + xv.z * xv.z + xv.w * xv.w;
#pragma unroll
  for (int m = 1; m < 64; m <<= 1) { s += __shfl_xor(s, m); ss += __shfl_xor(ss, m); }
  __shared__ float red[8];
  const int wv = threadIdx.x >> 6;
  if ((threadIdx.x & 63) == 0) { red[wv] = s; red[4 + wv] = ss; }
  __syncthreads();
  s  = red[0] + red[1] + red[2] + red[3];
  ss = red[4] + red[5] + red[6] + red[7];
  const float mu = s * (1.f / Dm);
  const float rstd = rsqrtf(ss * (1.f / Dm) - mu * mu + LNEPS);
  const float4 g  = *(const float4*)&gamma[d0];
  const float4 be = *(const float4*)&beta[d0];
  float4 y;
  y.x = (xv.x - mu) * rstd * g.x + be.x;
  y.y = (xv.y - mu) * rstd * g.y + be.y;
  y.z = (xv.z - mu) * rstd * g.z + be.z;
  y.w = (xv.w - mu) * rstd * g.w + be.w;
  *(float4*)&yf[row * Dm + d0] = y;
  if constexpr (WB) {
    s16x4 o;
    o[0] = f2bs(y.x); o[1] = f2bs(y.y); o[2] = f2bs(y.z); o[3] = f2bs(y.w);
    *(s16x4*)((short*)yb + row * Dm + d0) = o;
  }
}

// ---------------- mean pool ----------------
__global__ __launch_bounds__(256) void k_pool_part(const float* __restrict__ h3, float* __restrict__ part)
{
  const int b = blockIdx.x, lcn = blockIdx.y, dz = blockIdx.z;
  const int d = dz * 256 + threadIdx.x;
  float s = 0.f;
#pragma unroll 4
  for (int l = 0; l < 64; ++l)
    s += h3[((size_t)(b * Ll + lcn * 64 + l)) * Dm + d];
  part[((size_t)(b * 16 + lcn)) * Dm + d] = s;
}

__global__ __launch_bounds__(256) void k_pool_fin(const float* __restrict__ part, float* __restrict__ out)
{
  const int b = blockIdx.x;
  const int d = blockIdx.y * 256 + threadIdx.x;
  float s = 0.f;
#pragma unroll
  for (int c = 0; c < 16; ++c) s += part[((size_t)(b * 16 + c)) * Dm + d];
  out[b * Dm + d] = s * (1.f / Ll);
  out[(size_t)Mm + b * Dm + d] = 1.f / Ll;  // attn_tokens == 1/L analytically
}

extern "C" void kernel_launch(void* const* d_in, const int* in_sizes, int n_in,
                              void* d_out, int out_size, void* d_ws, size_t ws_size,
                              hipStream_t stream) {
  const int*   tids  = (const int*)  d_in[0];
  const float* vals  = (const float*)d_in[1];
  const float* dels  = (const float*)d_in[2];
  const float* temb  = (const float*)d_in[3];
  const float* Wv    = (const float*)d_in[4];
  const float* bv    = (const float*)d_in[5];
  const float* Wt    = (const float*)d_in[6];
  const float* bt    = (const float*)d_in[7];
  const float* Win   = (const float*)d_in[8];
  const float* bin   = (const float*)d_in[9];
  const float* Wout  = (const float*)d_in[10];
  const float* bout  = (const float*)d_in[11];
  const float* W1    = (const float*)d_in[12];
  const float* b1    = (const float*)d_in[13];
  const float* W2    = (const float*)d_in[14];
  const float* b2    = (const float*)d_in[15];
  const float* gamma = (const float*)d_in[16];
  const float* beta  = (const float*)d_in[17];
  float* out = (float*)d_out;

  char* w = (char*)d_ws;
  const size_t MB = 1ull << 20;
  float* hf    = (float*)(w + 0);         // [0,32)   h f32
  bf16*  hb    = (bf16*) (w + 32 * MB);   // [32,48)  h bf16
  bf16*  qkv   = (bf16*) (w + 48 * MB);   // [48,96)  qkv bf16
  bf16*  vtb   = (bf16*) (w + 96 * MB);   // [96,112) v^T bf16
  bf16*  attnb = (bf16*) (w + 112 * MB);  // [112,128) attn bf16
  float* x1    = (float*)(w + 48 * MB);   // [48,80)  h+attn_out (qkv dead)
  float* h2f   = (float*)(w + 80 * MB);   // [80,112) h2 f32
  bf16*  h2b   = (bf16*) (w + 32 * MB);   // [32,48)  h2 bf16 (hb dead)
  bf16*  ff1   = (bf16*) (w + 112 * MB);  // [112,128) relu(ff1) (attnb dead)
  float* x2    = (float*)(w + 0);         // [0,32)   h2+ff2 (hf dead)
  float* h3    = (float*)(w + 48 * MB);   // [48,80)  h3 (x1 dead)
  bf16*  WinB  = (bf16*) (w + 129 * MB);
  bf16*  WoutB = (bf16*) (w + 135 * MB);
  bf16*  W1B   = (bf16*) (w + 137 * MB);
  bf16*  W2B   = (bf16*) (w + 139 * MB);
  float* part  = (float*)(w + 141 * MB);

  k_f2b<<<3072, 256, 0, stream>>>(Win,  WinB);
  k_f2b<<<1024, 256, 0, stream>>>(Wout, WoutB);
  k_f2b<<<1024, 256, 0, stream>>>(W1,   W1B);
  k_f2b<<<1024, 256, 0, stream>>>(W2,   W2B);

  k_embed<<<Mm, 256, 0, stream>>>(tids, vals, dels, temb, Wv, bv, Wt, bt, hf, hb);

  k_gemm_bt<false, false, true, false><<<dim3(64, 24), 256, 0, stream>>>(
      hb, WinB, bin, nullptr, nullptr, qkv, 3072, 1024);

  k_vt<<<dim3(128, 16), 256, 0, stream>>>(qkv, vtb);
  k_attn<<<dim3(128, 8), 256, 0, stream>>>(qkv, vtb, attnb);

  k_gemm_bt<false, true, false, true><<<dim3(64, 8), 256, 0, stream>>>(
      attnb, WoutB, bout, hf, x1, nullptr, 1024, 1024);

  k_ln<true><<<Mm, 256, 0, stream>>>(x1, gamma, beta, h2f, h2b);

  k_gemm_bt<true, false, true, false><<<dim3(64, 8), 256, 0, stream>>>(
      h2b, W1B, b1, nullptr, nullptr, ff1, 1024, 1024);

  k_gemm_bt<false, true, false, true><<<dim3(64, 8), 256, 0, stream>>>(
      ff1, W2B, b2, h2f, x2, nullptr, 1024, 1024);

  k_ln<false><<<Mm, 256, 0, stream>>>(x2, gamma, beta, h3, nullptr);

  k_pool_part<<<dim3(8, 16, 4), 256, 0, stream>>>(h3, part);
  k_pool_fin<<<dim3(8, 4), 256, 0, stream>>>(part, out);
}

// Round 3
// 263.634 us; speedup vs baseline: 1.2043x; 1.0364x over previous
//
#include <hip/hip_runtime.h>
#include <hip/hip_bf16.h>

// EventSequenceEncoder: embed -> QKV gemm -> attention -> Wout(+res) -> LN ->
// FF1(relu) -> FF2(+res) -> LN -> mean-pool.  attn_tokens == 1/L analytically.
// R2: all GEMMs on an 8-phase counted-vmcnt template (T2 swizzle + T3/T4 + T5):
// BM=128,BN=256,BK=64, 8 waves(2x4), 512 thr, LDS 96KB dbuf, vmcnt(2) boundary.

#define Dm 1024
#define Hh 16
#define Bb 8
#define Ll 1024
#define Mm 8192
#define LNEPS 1e-5f

typedef __attribute__((ext_vector_type(8))) short s16x8;
typedef __attribute__((ext_vector_type(4))) short s16x4;
typedef __attribute__((ext_vector_type(4))) float f32x4;

using bf16 = __hip_bfloat16;

__device__ __forceinline__ short f2bs(float f) {
  return __builtin_bit_cast(short, __float2bfloat16(f));
}

__device__ __forceinline__ unsigned cvtpk(float lo, float hi) {
  unsigned r;
  asm("v_cvt_pk_bf16_f32 %0, %1, %2" : "=v"(r) : "v"(lo), "v"(hi));
  return r;
}

__device__ __forceinline__ void gload16(const void* g, void* l) {
  __builtin_amdgcn_global_load_lds(
      (__attribute__((address_space(1))) void*)g,
      (__attribute__((address_space(3))) void*)l, 16, 0, 0);
}

// ---------------- weight f32 -> bf16 ----------------
__global__ __launch_bounds__(256) void k_f2b(const float* __restrict__ x, bf16* __restrict__ y)
{
  const size_t i = ((size_t)blockIdx.x * 256 + threadIdx.x) * 4;
  const float4 v = *(const float4*)&x[i];
  s16x4 o;
  o[0] = f2bs(v.x); o[1] = f2bs(v.y); o[2] = f2bs(v.z); o[3] = f2bs(v.w);
  *(s16x4*)&y[i] = o;
}

// ---------------- fused embedding ----------------
__global__ __launch_bounds__(256) void k_embed(
    const int* __restrict__ tids, const float* __restrict__ vals, const float* __restrict__ dels,
    const float* __restrict__ temb, const float* __restrict__ Wv, const float* __restrict__ bv,
    const float* __restrict__ Wt, const float* __restrict__ bt,
    float* __restrict__ hf, bf16* __restrict__ hb)
{
  const int row = blockIdx.x;
  const int ty = tids[row];
  const float v = vals[row], dl = dels[row];
  const int d0 = threadIdx.x * 4;
  const float4 e  = *(const float4*)&temb[(size_t)ty * Dm + d0];
  const float4 wv = *(const float4*)&Wv[d0];
  const float4 c1 = *(const float4*)&bv[d0];
  const float4 wt = *(const float4*)&Wt[d0];
  const float4 c2 = *(const float4*)&bt[d0];
  float4 h;
  h.x = e.x + v * wv.x + c1.x + dl * wt.x + c2.x;
  h.y = e.y + v * wv.y + c1.y + dl * wt.y + c2.y;
  h.z = e.z + v * wv.z + c1.z + dl * wt.z + c2.z;
  h.w = e.w + v * wv.w + c1.w + dl * wt.w + c2.w;
  *(float4*)&hf[(size_t)row * Dm + d0] = h;
  s16x4 o;
  o[0] = f2bs(h.x); o[1] = f2bs(h.y); o[2] = f2bs(h.z); o[3] = f2bs(h.w);
  *(s16x4*)((short*)hb + (size_t)row * Dm + d0) = o;
}

// ---------------- 8-phase GEMM: out = A[M,K] @ Bt[N,K]^T + bias (+res) -------
// BM=128, BN=256, BK=64, 8 waves (2M x 4N), per-wave 64x64 out.
// LDS dbuf: per buf A[128][64] + B[256][64] bf16, XOR-swizzled (slot^(row&7)).
// Phases per K-tile: p0{rd A0,B0 | stage B0(t+1)} p1{rd A1 | stage B1(t+1)}
// p2{rd B1 | stage A0(t+2)} p3{stage A1(t+2)}; boundary s_waitcnt vmcnt(2).
template<bool RELU, bool OUTF, bool OUTB, bool RES>
__global__ __launch_bounds__(512) void k_gemm8(
    const bf16* __restrict__ A, const bf16* __restrict__ Bt,
    const float* __restrict__ bias, const float* __restrict__ res,
    float* __restrict__ outF, bf16* __restrict__ outB, const int N, const int K)
{
  __shared__ __attribute__((aligned(16))) short lds[49152];  // 2 x (8192 A + 16384 B)
  const int tid = threadIdx.x, lane = tid & 63, wave = tid >> 6;
  const int wr = wave >> 2, wc = wave & 3;
  const int l15 = lane & 15, lg = (lane >> 4) & 3;
  const int bm = blockIdx.x, bn = blockIdx.y;
  const int NT = K >> 6;

  const int rl = tid >> 3;                 // 0..63 staging row-in-half
  const int swz = ((tid & 7) ^ (rl & 7)) * 8;
  const bf16* aSrc = A  + (size_t)(bm * 128 + rl) * K + swz;
  const bf16* bSrc = Bt + (size_t)(bn * 256 + rl) * K + swz;

  f32x4 acc[4][4] = {};

  auto stageA = [&](int t, int h) {
    gload16(aSrc + (size_t)h * 64 * K + t * 64,
            &lds[(t & 1) * 24576 + h * 4096 + tid * 8]);
  };
  auto stageB = [&](int t, int h) {
    gload16(bSrc + (size_t)h * 128 * K + t * 64,
            &lds[(t & 1) * 24576 + 8192 + h * 8192 + tid * 8]);
    gload16(bSrc + (size_t)(h * 128 + 64) * K + t * 64,
            &lds[(t & 1) * 24576 + 8192 + h * 8192 + 4096 + tid * 8]);
  };

  // prologue: tile0 (A0,A1,B0,B1) -> buf0; A0,A1 of tile1 -> buf1
  stageA(0, 0); stageA(0, 1); stageB(0, 0); stageB(0, 1);
  if (NT > 1) { stageA(1, 0); stageA(1, 1); }
  asm volatile("s_waitcnt vmcnt(2)" ::: "memory");
  __builtin_amdgcn_sched_barrier(0);
  __builtin_amdgcn_s_barrier();

  for (int t = 0; t < NT; ++t) {
    const int cb = (t & 1) * 24576;
    s16x8 fa[4][2], fb[2][2];

    // ---- phase 0: read A0-half + B0-half; stage B0(t+1)
#pragma unroll
    for (int m = 0; m < 2; ++m)
#pragma unroll
      for (int ks = 0; ks < 2; ++ks) {
        const int row = wr * 64 + m * 16 + l15;
        fa[m][ks] = *(const s16x8*)&lds[cb + row * 64 + (((ks * 4 + lg) ^ (row & 7)) << 3)];
      }
#pragma unroll
    for (int n = 0; n < 2; ++n)
#pragma unroll
      for (int ks = 0; ks < 2; ++ks) {
        const int row = wc * 64 + n * 16 + l15;
        fb[n][ks] = *(const s16x8*)&lds[cb + 8192 + row * 64 + (((ks * 4 + lg) ^ (row & 7)) << 3)];
      }
    if (t + 1 < NT) stageB(t + 1, 0);
    __builtin_amdgcn_s_barrier();
    asm volatile("s_waitcnt lgkmcnt(0)" ::: "memory");
    __builtin_amdgcn_sched_barrier(0);
    __builtin_amdgcn_s_setprio(1);
#pragma unroll
    for (int m = 0; m < 2; ++m)
#pragma unroll
      for (int n = 0; n < 2; ++n)
#pragma unroll
        for (int ks = 0; ks < 2; ++ks)
          acc[m][n] = __builtin_amdgcn_mfma_f32_16x16x32_bf16(fa[m][ks], fb[n][ks], acc[m][n], 0, 0, 0);
    __builtin_amdgcn_s_setprio(0);
    __builtin_amdgcn_s_barrier();

    // ---- phase 1: read A1-half; stage B1(t+1)
#pragma unroll
    for (int m = 0; m < 2; ++m)
#pragma unroll
      for (int ks = 0; ks < 2; ++ks) {
        const int row = wr * 64 + (2 + m) * 16 + l15;
        fa[2 + m][ks] = *(const s16x8*)&lds[cb + row * 64 + (((ks * 4 + lg) ^ (row & 7)) << 3)];
      }
    if (t + 1 < NT) stageB(t + 1, 1);
    __builtin_amdgcn_s_barrier();
    asm volatile("s_waitcnt lgkmcnt(0)" ::: "memory");
    __builtin_amdgcn_sched_barrier(0);
    __builtin_amdgcn_s_setprio(1);
#pragma unroll
    for (int m = 0; m < 2; ++m)
#pragma unroll
      for (int n = 0; n < 2; ++n)
#pragma unroll
        for (int ks = 0; ks < 2; ++ks)
          acc[2 + m][n] = __builtin_amdgcn_mfma_f32_16x16x32_bf16(fa[2 + m][ks], fb[n][ks], acc[2 + m][n], 0, 0, 0);
    __builtin_amdgcn_s_setprio(0);
    __builtin_amdgcn_s_barrier();

    // ---- phase 2: read B1-half; stage A0(t+2) into current buf (A0 dead)
#pragma unroll
    for (int n = 0; n < 2; ++n)
#pragma unroll
      for (int ks = 0; ks < 2; ++ks) {
        const int row = wc * 64 + (2 + n) * 16 + l15;
        fb[n][ks] = *(const s16x8*)&lds[cb + 8192 + row * 64 + (((ks * 4 + lg) ^ (row & 7)) << 3)];
      }
    if (t + 2 < NT) stageA(t + 2, 0);
    __builtin_amdgcn_s_barrier();
    asm volatile("s_waitcnt lgkmcnt(0)" ::: "memory");
    __builtin_amdgcn_sched_barrier(0);
    __builtin_amdgcn_s_setprio(1);
#pragma unroll
    for (int m = 0; m < 2; ++m)
#pragma unroll
      for (int n = 0; n < 2; ++n)
#pragma unroll
        for (int ks = 0; ks < 2; ++ks)
          acc[m][2 + n] = __builtin_amdgcn_mfma_f32_16x16x32_bf16(fa[m][ks], fb[n][ks], acc[m][2 + n], 0, 0, 0);
    __builtin_amdgcn_s_setprio(0);
    __builtin_amdgcn_s_barrier();

    // ---- phase 3: stage A1(t+2); MFMA quadrant (1,1)
    if (t + 2 < NT) stageA(t + 2, 1);
    __builtin_amdgcn_s_barrier();
    __builtin_amdgcn_s_setprio(1);
#pragma unroll
    for (int m = 0; m < 2; ++m)
#pragma unroll
      for (int n = 0; n < 2; ++n)
#pragma unroll
        for (int ks = 0; ks < 2; ++ks)
          acc[2 + m][2 + n] = __builtin_amdgcn_mfma_f32_16x16x32_bf16(fa[2 + m][ks], fb[n][ks], acc[2 + m][2 + n], 0, 0, 0);
    __builtin_amdgcn_s_setprio(0);

    // ---- boundary: tile t+1 must be fully landed; A(t+2) may stay in flight
    if (t + 1 < NT) {
      if (t + 2 < NT) asm volatile("s_waitcnt vmcnt(2)" ::: "memory");
      else            asm volatile("s_waitcnt vmcnt(0)" ::: "memory");
      __builtin_amdgcn_sched_barrier(0);
      __builtin_amdgcn_s_barrier();
    }
  }

  // epilogue
#pragma unroll
  for (int n = 0; n < 4; ++n) {
    const int col = bn * 256 + wc * 64 + n * 16 + l15;
    const float bc = bias[col];
#pragma unroll
    for (int m = 0; m < 4; ++m) {
#pragma unroll
      for (int i = 0; i < 4; ++i) {
        const size_t row = (size_t)bm * 128 + wr * 64 + m * 16 + lg * 4 + i;
        float v = acc[m][n][i] + bc;
        if constexpr (RES)  v += res[row * N + col];
        if constexpr (RELU) v = fmaxf(v, 0.f);
        if constexpr (OUTF) outF[row * N + col] = v;
        if constexpr (OUTB) outB[row * N + col] = __float2bfloat16(v);
      }
    }
  }
}

// ---------------- V transpose: vt[b,h][dh][l] = v[b,l,h,dh] ----------------
__global__ __launch_bounds__(256) void k_vt(const bf16* __restrict__ qkv, bf16* __restrict__ vt)
{
  const int bh = blockIdx.x, lc = blockIdx.y;
  const int b = bh >> 4, h = bh & 15;
  __shared__ short tile[64][72];
  const int r = threadIdx.x >> 2;
  const int c0 = (threadIdx.x & 3) << 4;
  const short* src = (const short*)qkv + ((size_t)(b * Ll + lc * 64 + r)) * 3072 + 2048 + h * 64 + c0;
  const s16x8 x0 = *(const s16x8*)src;
  const s16x8 x1 = *(const s16x8*)(src + 8);
#pragma unroll
  for (int j = 0; j < 8; ++j) { tile[r][c0 + j] = x0[j]; tile[r][c0 + 8 + j] = x1[j]; }
  __syncthreads();
  s16x8 y0, y1;
#pragma unroll
  for (int j = 0; j < 8; ++j) { y0[j] = tile[c0 + j][r]; y1[j] = tile[c0 + 8 + j][r]; }
  short* dst = (short*)vt + ((size_t)(bh * 64 + r)) * Ll + lc * 64 + c0;
  *(s16x8*)dst = y0;
  *(s16x8*)(dst + 8) = y1;
}

// ---------------- attention: swapped QK^T, wave-private P, QBLK=128 ----------
__global__ __launch_bounds__(256) void k_attn(
    const bf16* __restrict__ qkv, const bf16* __restrict__ vt, bf16* __restrict__ attnb)
{
  const int bh = blockIdx.x;
  const int qb = blockIdx.y;
  const int b = bh >> 4, h = bh & 15;
  __shared__ __attribute__((aligned(16))) short lK[4096];
  __shared__ __attribute__((aligned(16))) short lV[4096];
  __shared__ __attribute__((aligned(16))) short lP[8192];
  const int tid = threadIdx.x, lane = tid & 63, wave = tid >> 6;
  const int l15 = lane & 15, lg = lane >> 4;
  const int qrow = wave * 32;
  const int l7 = l15 & 7;

  s16x8 qf[2][2];
#pragma unroll
  for (int mq = 0; mq < 2; ++mq)
#pragma unroll
    for (int ks = 0; ks < 2; ++ks)
      qf[mq][ks] = *(const s16x8*)((const short*)qkv +
          ((size_t)(b * Ll + qb * 128 + qrow + mq * 16 + l15)) * 3072 + h * 64 + ks * 32 + lg * 8);

  f32x4 o[2][4] = {};
  float rs[2] = {0.f, 0.f};

  const int sr = tid >> 3;
  const int swz = (tid & 7) ^ (sr & 7);

  for (int mc = 0; mc < 16; ++mc) {
    __syncthreads();
    {
      const bf16* gk = qkv + ((size_t)(b * Ll + mc * 64 + sr)) * 3072 + 1024 + h * 64 + swz * 8;
      gload16(gk,                     &lK[tid * 8]);
      gload16(gk + (size_t)32 * 3072, &lK[2048 + tid * 8]);
      const bf16* gv = vt + ((size_t)(bh * 64 + sr)) * Ll + mc * 64 + swz * 8;
      gload16(gv,                   &lV[tid * 8]);
      gload16(gv + (size_t)32 * Ll, &lV[2048 + tid * 8]);
    }
    __syncthreads();

    f32x4 st[2][4] = {};
    __builtin_amdgcn_s_setprio(1);
#pragma unroll
    for (int ks = 0; ks < 2; ++ks) {
#pragma unroll
      for (int n = 0; n < 4; ++n) {
        const int kr = n * 16 + l15;
        const s16x8 kf = *(const s16x8*)&lK[kr * 64 + (((ks * 4 + lg) ^ l7) << 3)];
        st[0][n] = __builtin_amdgcn_mfma_f32_16x16x32_bf16(kf, qf[0][ks], st[0][n], 0, 0, 0);
        st[1][n] = __builtin_amdgcn_mfma_f32_16x16x32_bf16(kf, qf[1][ks], st[1][n], 0, 0, 0);
      }
    }
    __builtin_amdgcn_s_setprio(0);

#pragma unroll
    for (int mq = 0; mq < 2; ++mq) {
      const int qr = qrow + mq * 16 + l15;
      short* prow = &lP[qr * 64];
      float loc = 0.f;
#pragma unroll
      for (int n = 0; n < 4; ++n) {
        const float e0 = __expf(st[mq][n][0] * 0.125f);
        const float e1 = __expf(st[mq][n][1] * 0.125f);
        const float e2 = __expf(st[mq][n][2] * 0.125f);
        const float e3 = __expf(st[mq][n][3] * 0.125f);
        loc += (e0 + e1) + (e2 + e3);
        const unsigned c0 = cvtpk(e0, e1);
        const unsigned c1 = cvtpk(e2, e3);
        const int col0 = n * 16 + lg * 4;
        const int scol = ((((col0 >> 3) ^ (qr & 7)) << 3) | (col0 & 7));
        *(unsigned*)&prow[scol]     = c0;
        *(unsigned*)&prow[scol + 2] = c1;
      }
      rs[mq] += loc;
    }

    __builtin_amdgcn_s_setprio(1);
#pragma unroll
    for (int ks = 0; ks < 2; ++ks) {
      s16x8 pa[2];
#pragma unroll
      for (int mq = 0; mq < 2; ++mq) {
        const int qr = qrow + mq * 16 + l15;
        pa[mq] = *(const s16x8*)&lP[qr * 64 + (((ks * 4 + lg) ^ (qr & 7)) << 3)];
      }
#pragma unroll
      for (int dn = 0; dn < 4; ++dn) {
        const int vr = dn * 16 + l15;
        const s16x8 vf = *(const s16x8*)&lV[vr * 64 + (((ks * 4 + lg) ^ l7) << 3)];
        o[0][dn] = __builtin_amdgcn_mfma_f32_16x16x32_bf16(pa[0], vf, o[0][dn], 0, 0, 0);
        o[1][dn] = __builtin_amdgcn_mfma_f32_16x16x32_bf16(pa[1], vf, o[1][dn], 0, 0, 0);
      }
    }
    __builtin_amdgcn_s_setprio(0);
  }

#pragma unroll
  for (int mq = 0; mq < 2; ++mq) {
    rs[mq] += __shfl_xor(rs[mq], 16);
    rs[mq] += __shfl_xor(rs[mq], 32);
  }
#pragma unroll
  for (int mq = 0; mq < 2; ++mq) {
    float inv[4];
#pragma unroll
    for (int i = 0; i < 4; ++i)
      inv[i] = 1.f / __shfl(rs[mq], lg * 4 + i);
#pragma unroll
    for (int dn = 0; dn < 4; ++dn) {
#pragma unroll
      for (int i = 0; i < 4; ++i) {
        const int q = qb * 128 + qrow + mq * 16 + lg * 4 + i;
        attnb[((size_t)(b * Ll + q)) * Dm + h * 64 + dn * 16 + l15] =
            __float2bfloat16(o[mq][dn][i] * inv[i]);
      }
    }
  }
}

// ---------------- LayerNorm (one row per block) ----------------
template<bool WB>
__global__ __launch_bounds__(256) void k_ln(const float* __restrict__ x,
    const float* __restrict__ gamma, const float* __restrict__ beta,
    float* __restrict__ yf, bf16* __restrict__ yb)
{
  const size_t row = blockIdx.x;
  const int d0 = threadIdx.x * 4;
  const float4 xv = *(const float4*)&x[row * Dm + d0];
  float s  = xv.x + xv.y + xv.z + xv.w;
  float ss = xv.x * xv.x + xv.y * xv.y + xv.z * xv.z + xv.w * xv.w;
#pragma unroll
  for (int m = 1; m < 64; m <<= 1) { s += __shfl_xor(s, m); ss += __shfl_xor(ss, m); }
  __shared__ float red[8];
  const int wv = threadIdx.x >> 6;
  if ((threadIdx.x & 63) == 0) { red[wv] = s; red[4 + wv] = ss; }
  __syncthreads();
  s  = red[0] + red[1] + red[2] + red[3];
  ss = red[4] + red[5] + red[6] + red[7];
  const float mu = s * (1.f / Dm);
  const float rstd = rsqrtf(ss * (1.f / Dm) - mu * mu + LNEPS);
  const float4 g  = *(const float4*)&gamma[d0];
  const float4 be = *(const float4*)&beta[d0];
  float4 y;
  y.x = (xv.x - mu) * rstd * g.x + be.x;
  y.y = (xv.y - mu) * rstd * g.y + be.y;
  y.z = (xv.z - mu) * rstd * g.z + be.z;
  y.w = (xv.w - mu) * rstd * g.w + be.w;
  *(float4*)&yf[row * Dm + d0] = y;
  if constexpr (WB) {
    s16x4 o;
    o[0] = f2bs(y.x); o[1] = f2bs(y.y); o[2] = f2bs(y.z); o[3] = f2bs(y.w);
    *(s16x4*)((short*)yb + row * Dm + d0) = o;
  }
}

// ---------------- mean pool ----------------
__global__ __launch_bounds__(256) void k_pool_part(const float* __restrict__ h3, float* __restrict__ part)
{
  const int b = blockIdx.x, lcn = blockIdx.y, dz = blockIdx.z;
  const int d = dz * 256 + threadIdx.x;
  float s = 0.f;
#pragma unroll 4
  for (int l = 0; l < 64; ++l)
    s += h3[((size_t)(b * Ll + lcn * 64 + l)) * Dm + d];
  part[((size_t)(b * 16 + lcn)) * Dm + d] = s;
}

__global__ __launch_bounds__(256) void k_pool_fin(const float* __restrict__ part, float* __restrict__ out)
{
  const int b = blockIdx.x;
  const int d = blockIdx.y * 256 + threadIdx.x;
  float s = 0.f;
#pragma unroll
  for (int c = 0; c < 16; ++c) s += part[((size_t)(b * 16 + c)) * Dm + d];
  out[b * Dm + d] = s * (1.f / Ll);
  out[(size_t)Mm + b * Dm + d] = 1.f / Ll;  // attn_tokens == 1/L analytically
}

extern "C" void kernel_launch(void* const* d_in, const int* in_sizes, int n_in,
                              void* d_out, int out_size, void* d_ws, size_t ws_size,
                              hipStream_t stream) {
  const int*   tids  = (const int*)  d_in[0];
  const float* vals  = (const float*)d_in[1];
  const float* dels  = (const float*)d_in[2];
  const float* temb  = (const float*)d_in[3];
  const float* Wv    = (const float*)d_in[4];
  const float* bv    = (const float*)d_in[5];
  const float* Wt    = (const float*)d_in[6];
  const float* bt    = (const float*)d_in[7];
  const float* Win   = (const float*)d_in[8];
  const float* bin   = (const float*)d_in[9];
  const float* Wout  = (const float*)d_in[10];
  const float* bout  = (const float*)d_in[11];
  const float* W1    = (const float*)d_in[12];
  const float* b1    = (const float*)d_in[13];
  const float* W2    = (const float*)d_in[14];
  const float* b2    = (const float*)d_in[15];
  const float* gamma = (const float*)d_in[16];
  const float* beta  = (const float*)d_in[17];
  float* out = (float*)d_out;

  char* w = (char*)d_ws;
  const size_t MB = 1ull << 20;
  float* hf    = (float*)(w + 0);         // [0,32)   h f32
  bf16*  hb    = (bf16*) (w + 32 * MB);   // [32,48)  h bf16
  bf16*  qkv   = (bf16*) (w + 48 * MB);   // [48,96)  qkv bf16
  bf16*  vtb   = (bf16*) (w + 96 * MB);   // [96,112) v^T bf16
  bf16*  attnb = (bf16*) (w + 112 * MB);  // [112,128) attn bf16
  float* x1    = (float*)(w + 48 * MB);   // [48,80)  h+attn_out (qkv dead)
  float* h2f   = (float*)(w + 80 * MB);   // [80,112) h2 f32
  bf16*  h2b   = (bf16*) (w + 32 * MB);   // [32,48)  h2 bf16 (hb dead)
  bf16*  ff1   = (bf16*) (w + 112 * MB);  // [112,128) relu(ff1) (attnb dead)
  float* x2    = (float*)(w + 0);         // [0,32)   h2+ff2 (hf dead)
  float* h3    = (float*)(w + 48 * MB);   // [48,80)  h3 (x1 dead)
  bf16*  WinB  = (bf16*) (w + 129 * MB);
  bf16*  WoutB = (bf16*) (w + 135 * MB);
  bf16*  W1B   = (bf16*) (w + 137 * MB);
  bf16*  W2B   = (bf16*) (w + 139 * MB);
  float* part  = (float*)(w + 141 * MB);

  k_f2b<<<3072, 256, 0, stream>>>(Win,  WinB);
  k_f2b<<<1024, 256, 0, stream>>>(Wout, WoutB);
  k_f2b<<<1024, 256, 0, stream>>>(W1,   W1B);
  k_f2b<<<1024, 256, 0, stream>>>(W2,   W2B);

  k_embed<<<Mm, 256, 0, stream>>>(tids, vals, dels, temb, Wv, bv, Wt, bt, hf, hb);

  k_gemm8<false, false, true, false><<<dim3(64, 12), 512, 0, stream>>>(
      hb, WinB, bin, nullptr, nullptr, qkv, 3072, 1024);

  k_vt<<<dim3(128, 16), 256, 0, stream>>>(qkv, vtb);
  k_attn<<<dim3(128, 8), 256, 0, stream>>>(qkv, vtb, attnb);

  k_gemm8<false, true, false, true><<<dim3(64, 4), 512, 0, stream>>>(
      attnb, WoutB, bout, hf, x1, nullptr, 1024, 1024);

  k_ln<true><<<Mm, 256, 0, stream>>>(x1, gamma, beta, h2f, h2b);

  k_gemm8<true, false, true, false><<<dim3(64, 4), 512, 0, stream>>>(
      h2b, W1B, b1, nullptr, nullptr, ff1, 1024, 1024);

  k_gemm8<false, true, false, true><<<dim3(64, 4), 512, 0, stream>>>(
      ff1, W2B, b2, h2f, x2, nullptr, 1024, 1024);

  k_ln<false><<<Mm, 256, 0, stream>>>(x2, gamma, beta, h3, nullptr);

  k_pool_part<<<dim3(8, 16, 4), 256, 0, stream>>>(h3, part);
  k_pool_fin<<<dim3(8, 4), 256, 0, stream>>>(part, out);
}

// Round 4
// 257.172 us; speedup vs baseline: 1.2346x; 1.0251x over previous
//
#include <hip/hip_runtime.h>
#include <hip/hip_bf16.h>

// EventSequenceEncoder: embed -> QKV gemm -> attention -> Wout(+res) -> LN ->
// FF1(relu) -> FF2(+res) -> LN -> mean-pool.  attn_tokens == 1/L analytically.
// R3: GEMM phases merged 4->2 per K-tile (16 MFMA per barrier-pair, was 8).
// BM=128,BN=256,BK=64, 8 waves(2x4), 512 thr, LDS 96KB dbuf, vmcnt(2) boundary.

#define Dm 1024
#define Hh 16
#define Bb 8
#define Ll 1024
#define Mm 8192
#define LNEPS 1e-5f

typedef __attribute__((ext_vector_type(8))) short s16x8;
typedef __attribute__((ext_vector_type(4))) short s16x4;
typedef __attribute__((ext_vector_type(4))) float f32x4;

using bf16 = __hip_bfloat16;

__device__ __forceinline__ short f2bs(float f) {
  return __builtin_bit_cast(short, __float2bfloat16(f));
}

__device__ __forceinline__ unsigned cvtpk(float lo, float hi) {
  unsigned r;
  asm("v_cvt_pk_bf16_f32 %0, %1, %2" : "=v"(r) : "v"(lo), "v"(hi));
  return r;
}

__device__ __forceinline__ void gload16(const void* g, void* l) {
  __builtin_amdgcn_global_load_lds(
      (__attribute__((address_space(1))) void*)g,
      (__attribute__((address_space(3))) void*)l, 16, 0, 0);
}

// ---------------- weight f32 -> bf16 ----------------
__global__ __launch_bounds__(256) void k_f2b(const float* __restrict__ x, bf16* __restrict__ y)
{
  const size_t i = ((size_t)blockIdx.x * 256 + threadIdx.x) * 4;
  const float4 v = *(const float4*)&x[i];
  s16x4 o;
  o[0] = f2bs(v.x); o[1] = f2bs(v.y); o[2] = f2bs(v.z); o[3] = f2bs(v.w);
  *(s16x4*)&y[i] = o;
}

// ---------------- fused embedding ----------------
__global__ __launch_bounds__(256) void k_embed(
    const int* __restrict__ tids, const float* __restrict__ vals, const float* __restrict__ dels,
    const float* __restrict__ temb, const float* __restrict__ Wv, const float* __restrict__ bv,
    const float* __restrict__ Wt, const float* __restrict__ bt,
    float* __restrict__ hf, bf16* __restrict__ hb)
{
  const int row = blockIdx.x;
  const int ty = tids[row];
  const float v = vals[row], dl = dels[row];
  const int d0 = threadIdx.x * 4;
  const float4 e  = *(const float4*)&temb[(size_t)ty * Dm + d0];
  const float4 wv = *(const float4*)&Wv[d0];
  const float4 c1 = *(const float4*)&bv[d0];
  const float4 wt = *(const float4*)&Wt[d0];
  const float4 c2 = *(const float4*)&bt[d0];
  float4 h;
  h.x = e.x + v * wv.x + c1.x + dl * wt.x + c2.x;
  h.y = e.y + v * wv.y + c1.y + dl * wt.y + c2.y;
  h.z = e.z + v * wv.z + c1.z + dl * wt.z + c2.z;
  h.w = e.w + v * wv.w + c1.w + dl * wt.w + c2.w;
  *(float4*)&hf[(size_t)row * Dm + d0] = h;
  s16x4 o;
  o[0] = f2bs(h.x); o[1] = f2bs(h.y); o[2] = f2bs(h.z); o[3] = f2bs(h.w);
  *(s16x4*)((short*)hb + (size_t)row * Dm + d0) = o;
}

// ---------------- 2-subphase GEMM: out = A[M,K] @ Bt[N,K]^T + bias (+res) ----
// BM=128, BN=256, BK=64, 8 waves (2M x 4N), per-wave 64x64 out.
// LDS dbuf: per buf A[128][64] + B[256][64] bf16, XOR-swizzled (slot^(row&7)).
// SP0{rd fa(8)+fb01(4) | stage B(t+1) -> 16 MFMA}  SP1{rd fb23(4) | stage
// A(t+2) -> 16 MFMA}; boundary s_waitcnt vmcnt(2), never 0 mid-loop.
template<bool RELU, bool OUTF, bool OUTB, bool RES>
__global__ __launch_bounds__(512) void k_gemm8(
    const bf16* __restrict__ A, const bf16* __restrict__ Bt,
    const float* __restrict__ bias, const float* __restrict__ res,
    float* __restrict__ outF, bf16* __restrict__ outB, const int N, const int K)
{
  __shared__ __attribute__((aligned(16))) short lds[49152];  // 2 x (8192 A + 16384 B)
  const int tid = threadIdx.x, lane = tid & 63, wave = tid >> 6;
  const int wr = wave >> 2, wc = wave & 3;
  const int l15 = lane & 15, lg = (lane >> 4) & 3;
  const int bm = blockIdx.x, bn = blockIdx.y;
  const int NT = K >> 6;

  const int rl = tid >> 3;                 // 0..63 staging row-in-half
  const int swz = ((tid & 7) ^ (rl & 7)) * 8;
  const bf16* aSrc = A  + (size_t)(bm * 128 + rl) * K + swz;
  const bf16* bSrc = Bt + (size_t)(bn * 256 + rl) * K + swz;

  f32x4 acc[4][4] = {};

  auto stageA = [&](int t, int h) {
    gload16(aSrc + (size_t)h * 64 * K + t * 64,
            &lds[(t & 1) * 24576 + h * 4096 + tid * 8]);
  };
  auto stageB = [&](int t, int h) {
    gload16(bSrc + (size_t)h * 128 * K + t * 64,
            &lds[(t & 1) * 24576 + 8192 + h * 8192 + tid * 8]);
    gload16(bSrc + (size_t)(h * 128 + 64) * K + t * 64,
            &lds[(t & 1) * 24576 + 8192 + h * 8192 + 4096 + tid * 8]);
  };

  // prologue: tile0 (A0,A1,B0,B1) -> buf0; A0,A1 of tile1 -> buf1
  stageA(0, 0); stageA(0, 1); stageB(0, 0); stageB(0, 1);
  if (NT > 1) { stageA(1, 0); stageA(1, 1); }
  asm volatile("s_waitcnt vmcnt(2)" ::: "memory");
  __builtin_amdgcn_sched_barrier(0);
  __builtin_amdgcn_s_barrier();

  for (int t = 0; t < NT; ++t) {
    const int cb = (t & 1) * 24576;
    s16x8 fa[4][2], fb[2][2];

    // ---- SP0: read all fa + fb(n=0,1); stage B(t+1) both halves
#pragma unroll
    for (int m = 0; m < 4; ++m)
#pragma unroll
      for (int ks = 0; ks < 2; ++ks) {
        const int row = wr * 64 + m * 16 + l15;
        fa[m][ks] = *(const s16x8*)&lds[cb + row * 64 + (((ks * 4 + lg) ^ (row & 7)) << 3)];
      }
#pragma unroll
    for (int n = 0; n < 2; ++n)
#pragma unroll
      for (int ks = 0; ks < 2; ++ks) {
        const int row = wc * 64 + n * 16 + l15;
        fb[n][ks] = *(const s16x8*)&lds[cb + 8192 + row * 64 + (((ks * 4 + lg) ^ (row & 7)) << 3)];
      }
    if (t + 1 < NT) { stageB(t + 1, 0); stageB(t + 1, 1); }
    __builtin_amdgcn_s_barrier();
    asm volatile("s_waitcnt lgkmcnt(0)" ::: "memory");
    __builtin_amdgcn_sched_barrier(0);
    __builtin_amdgcn_s_setprio(1);
#pragma unroll
    for (int m = 0; m < 4; ++m)
#pragma unroll
      for (int n = 0; n < 2; ++n)
#pragma unroll
        for (int ks = 0; ks < 2; ++ks)
          acc[m][n] = __builtin_amdgcn_mfma_f32_16x16x32_bf16(fa[m][ks], fb[n][ks], acc[m][n], 0, 0, 0);
    __builtin_amdgcn_s_setprio(0);
    __builtin_amdgcn_s_barrier();

    // ---- SP1: read fb(n=2,3); stage A(t+2) into current buf (A region dead)
#pragma unroll
    for (int n = 0; n < 2; ++n)
#pragma unroll
      for (int ks = 0; ks < 2; ++ks) {
        const int row = wc * 64 + (2 + n) * 16 + l15;
        fb[n][ks] = *(const s16x8*)&lds[cb + 8192 + row * 64 + (((ks * 4 + lg) ^ (row & 7)) << 3)];
      }
    if (t + 2 < NT) { stageA(t + 2, 0); stageA(t + 2, 1); }
    __builtin_amdgcn_s_barrier();
    asm volatile("s_waitcnt lgkmcnt(0)" ::: "memory");
    __builtin_amdgcn_sched_barrier(0);
    __builtin_amdgcn_s_setprio(1);
#pragma unroll
    for (int m = 0; m < 4; ++m)
#pragma unroll
      for (int n = 0; n < 2; ++n)
#pragma unroll
        for (int ks = 0; ks < 2; ++ks)
          acc[m][2 + n] = __builtin_amdgcn_mfma_f32_16x16x32_bf16(fa[m][ks], fb[n][ks], acc[m][2 + n], 0, 0, 0);
    __builtin_amdgcn_s_setprio(0);

    // ---- boundary: tile t+1 must be fully landed; A(t+2) may stay in flight
    if (t + 1 < NT) {
      if (t + 2 < NT) asm volatile("s_waitcnt vmcnt(2)" ::: "memory");
      else            asm volatile("s_waitcnt vmcnt(0)" ::: "memory");
      __builtin_amdgcn_sched_barrier(0);
      __builtin_amdgcn_s_barrier();
    }
  }

  // epilogue
#pragma unroll
  for (int n = 0; n < 4; ++n) {
    const int col = bn * 256 + wc * 64 + n * 16 + l15;
    const float bc = bias[col];
#pragma unroll
    for (int m = 0; m < 4; ++m) {
#pragma unroll
      for (int i = 0; i < 4; ++i) {
        const size_t row = (size_t)bm * 128 + wr * 64 + m * 16 + lg * 4 + i;
        float v = acc[m][n][i] + bc;
        if constexpr (RES)  v += res[row * N + col];
        if constexpr (RELU) v = fmaxf(v, 0.f);
        if constexpr (OUTF) outF[row * N + col] = v;
        if constexpr (OUTB) outB[row * N + col] = __float2bfloat16(v);
      }
    }
  }
}

// ---------------- V transpose: vt[b,h][dh][l] = v[b,l,h,dh] ----------------
__global__ __launch_bounds__(256) void k_vt(const bf16* __restrict__ qkv, bf16* __restrict__ vt)
{
  const int bh = blockIdx.x, lc = blockIdx.y;
  const int b = bh >> 4, h = bh & 15;
  __shared__ short tile[64][72];
  const int r = threadIdx.x >> 2;
  const int c0 = (threadIdx.x & 3) << 4;
  const short* src = (const short*)qkv + ((size_t)(b * Ll + lc * 64 + r)) * 3072 + 2048 + h * 64 + c0;
  const s16x8 x0 = *(const s16x8*)src;
  const s16x8 x1 = *(const s16x8*)(src + 8);
#pragma unroll
  for (int j = 0; j < 8; ++j) { tile[r][c0 + j] = x0[j]; tile[r][c0 + 8 + j] = x1[j]; }
  __syncthreads();
  s16x8 y0, y1;
#pragma unroll
  for (int j = 0; j < 8; ++j) { y0[j] = tile[c0 + j][r]; y1[j] = tile[c0 + 8 + j][r]; }
  short* dst = (short*)vt + ((size_t)(bh * 64 + r)) * Ll + lc * 64 + c0;
  *(s16x8*)dst = y0;
  *(s16x8*)(dst + 8) = y1;
}

// ---------------- attention: swapped QK^T, wave-private P, QBLK=128 ----------
__global__ __launch_bounds__(256) void k_attn(
    const bf16* __restrict__ qkv, const bf16* __restrict__ vt, bf16* __restrict__ attnb)
{
  const int bh = blockIdx.x;
  const int qb = blockIdx.y;
  const int b = bh >> 4, h = bh & 15;
  __shared__ __attribute__((aligned(16))) short lK[4096];
  __shared__ __attribute__((aligned(16))) short lV[4096];
  __shared__ __attribute__((aligned(16))) short lP[8192];
  const int tid = threadIdx.x, lane = tid & 63, wave = tid >> 6;
  const int l15 = lane & 15, lg = lane >> 4;
  const int qrow = wave * 32;
  const int l7 = l15 & 7;

  s16x8 qf[2][2];
#pragma unroll
  for (int mq = 0; mq < 2; ++mq)
#pragma unroll
    for (int ks = 0; ks < 2; ++ks)
      qf[mq][ks] = *(const s16x8*)((const short*)qkv +
          ((size_t)(b * Ll + qb * 128 + qrow + mq * 16 + l15)) * 3072 + h * 64 + ks * 32 + lg * 8);

  f32x4 o[2][4] = {};
  float rs[2] = {0.f, 0.f};

  const int sr = tid >> 3;
  const int swz = (tid & 7) ^ (sr & 7);

  for (int mc = 0; mc < 16; ++mc) {
    __syncthreads();
    {
      const bf16* gk = qkv + ((size_t)(b * Ll + mc * 64 + sr)) * 3072 + 1024 + h * 64 + swz * 8;
      gload16(gk,                     &lK[tid * 8]);
      gload16(gk + (size_t)32 * 3072, &lK[2048 + tid * 8]);
      const bf16* gv = vt + ((size_t)(bh * 64 + sr)) * Ll + mc * 64 + swz * 8;
      gload16(gv,                   &lV[tid * 8]);
      gload16(gv + (size_t)32 * Ll, &lV[2048 + tid * 8]);
    }
    __syncthreads();

    f32x4 st[2][4] = {};
    __builtin_amdgcn_s_setprio(1);
#pragma unroll
    for (int ks = 0; ks < 2; ++ks) {
#pragma unroll
      for (int n = 0; n < 4; ++n) {
        const int kr = n * 16 + l15;
        const s16x8 kf = *(const s16x8*)&lK[kr * 64 + (((ks * 4 + lg) ^ l7) << 3)];
        st[0][n] = __builtin_amdgcn_mfma_f32_16x16x32_bf16(kf, qf[0][ks], st[0][n], 0, 0, 0);
        st[1][n] = __builtin_amdgcn_mfma_f32_16x16x32_bf16(kf, qf[1][ks], st[1][n], 0, 0, 0);
      }
    }
    __builtin_amdgcn_s_setprio(0);

#pragma unroll
    for (int mq = 0; mq < 2; ++mq) {
      const int qr = qrow + mq * 16 + l15;
      short* prow = &lP[qr * 64];
      float loc = 0.f;
#pragma unroll
      for (int n = 0; n < 4; ++n) {
        const float e0 = __expf(st[mq][n][0] * 0.125f);
        const float e1 = __expf(st[mq][n][1] * 0.125f);
        const float e2 = __expf(st[mq][n][2] * 0.125f);
        const float e3 = __expf(st[mq][n][3] * 0.125f);
        loc += (e0 + e1) + (e2 + e3);
        const unsigned c0 = cvtpk(e0, e1);
        const unsigned c1 = cvtpk(e2, e3);
        const int col0 = n * 16 + lg * 4;
        const int scol = ((((col0 >> 3) ^ (qr & 7)) << 3) | (col0 & 7));
        *(unsigned*)&prow[scol]     = c0;
        *(unsigned*)&prow[scol + 2] = c1;
      }
      rs[mq] += loc;
    }

    __builtin_amdgcn_s_setprio(1);
#pragma unroll
    for (int ks = 0; ks < 2; ++ks) {
      s16x8 pa[2];
#pragma unroll
      for (int mq = 0; mq < 2; ++mq) {
        const int qr = qrow + mq * 16 + l15;
        pa[mq] = *(const s16x8*)&lP[qr * 64 + (((ks * 4 + lg) ^ (qr & 7)) << 3)];
      }
#pragma unroll
      for (int dn = 0; dn < 4; ++dn) {
        const int vr = dn * 16 + l15;
        const s16x8 vf = *(const s16x8*)&lV[vr * 64 + (((ks * 4 + lg) ^ l7) << 3)];
        o[0][dn] = __builtin_amdgcn_mfma_f32_16x16x32_bf16(pa[0], vf, o[0][dn], 0, 0, 0);
        o[1][dn] = __builtin_amdgcn_mfma_f32_16x16x32_bf16(pa[1], vf, o[1][dn], 0, 0, 0);
      }
    }
    __builtin_amdgcn_s_setprio(0);
  }

#pragma unroll
  for (int mq = 0; mq < 2; ++mq) {
    rs[mq] += __shfl_xor(rs[mq], 16);
    rs[mq] += __shfl_xor(rs[mq], 32);
  }
#pragma unroll
  for (int mq = 0; mq < 2; ++mq) {
    float inv[4];
#pragma unroll
    for (int i = 0; i < 4; ++i)
      inv[i] = 1.f / __shfl(rs[mq], lg * 4 + i);
#pragma unroll
    for (int dn = 0; dn < 4; ++dn) {
#pragma unroll
      for (int i = 0; i < 4; ++i) {
        const int q = qb * 128 + qrow + mq * 16 + lg * 4 + i;
        attnb[((size_t)(b * Ll + q)) * Dm + h * 64 + dn * 16 + l15] =
            __float2bfloat16(o[mq][dn][i] * inv[i]);
      }
    }
  }
}

// ---------------- LayerNorm (one row per block) ----------------
template<bool WB>
__global__ __launch_bounds__(256) void k_ln(const float* __restrict__ x,
    const float* __restrict__ gamma, const float* __restrict__ beta,
    float* __restrict__ yf, bf16* __restrict__ yb)
{
  const size_t row = blockIdx.x;
  const int d0 = threadIdx.x * 4;
  const float4 xv = *(const float4*)&x[row * Dm + d0];
  float s  = xv.x + xv.y + xv.z + xv.w;
  float ss = xv.x * xv.x + xv.y * xv.y + xv.z * xv.z + xv.w * xv.w;
#pragma unroll
  for (int m = 1; m < 64; m <<= 1) { s += __shfl_xor(s, m); ss += __shfl_xor(ss, m); }
  __shared__ float red[8];
  const int wv = threadIdx.x >> 6;
  if ((threadIdx.x & 63) == 0) { red[wv] = s; red[4 + wv] = ss; }
  __syncthreads();
  s  = red[0] + red[1] + red[2] + red[3];
  ss = red[4] + red[5] + red[6] + red[7];
  const float mu = s * (1.f / Dm);
  const float rstd = rsqrtf(ss * (1.f / Dm) - mu * mu + LNEPS);
  const float4 g  = *(const float4*)&gamma[d0];
  const float4 be = *(const float4*)&beta[d0];
  float4 y;
  y.x = (xv.x - mu) * rstd * g.x + be.x;
  y.y = (xv.y - mu) * rstd * g.y + be.y;
  y.z = (xv.z - mu) * rstd * g.z + be.z;
  y.w = (xv.w - mu) * rstd * g.w + be.w;
  *(float4*)&yf[row * Dm + d0] = y;
  if constexpr (WB) {
    s16x4 o;
    o[0] = f2bs(y.x); o[1] = f2bs(y.y); o[2] = f2bs(y.z); o[3] = f2bs(y.w);
    *(s16x4*)((short*)yb + row * Dm + d0) = o;
  }
}

// ---------------- mean pool ----------------
__global__ __launch_bounds__(256) void k_pool_part(const float* __restrict__ h3, float* __restrict__ part)
{
  const int b = blockIdx.x, lcn = blockIdx.y, dz = blockIdx.z;
  const int d = dz * 256 + threadIdx.x;
  float s = 0.f;
#pragma unroll 4
  for (int l = 0; l < 64; ++l)
    s += h3[((size_t)(b * Ll + lcn * 64 + l)) * Dm + d];
  part[((size_t)(b * 16 + lcn)) * Dm + d] = s;
}

__global__ __launch_bounds__(256) void k_pool_fin(const float* __restrict__ part, float* __restrict__ out)
{
  const int b = blockIdx.x;
  const int d = blockIdx.y * 256 + threadIdx.x;
  float s = 0.f;
#pragma unroll
  for (int c = 0; c < 16; ++c) s += part[((size_t)(b * 16 + c)) * Dm + d];
  out[b * Dm + d] = s * (1.f / Ll);
  out[(size_t)Mm + b * Dm + d] = 1.f / Ll;  // attn_tokens == 1/L analytically
}

extern "C" void kernel_launch(void* const* d_in, const int* in_sizes, int n_in,
                              void* d_out, int out_size, void* d_ws, size_t ws_size,
                              hipStream_t stream) {
  const int*   tids  = (const int*)  d_in[0];
  const float* vals  = (const float*)d_in[1];
  const float* dels  = (const float*)d_in[2];
  const float* temb  = (const float*)d_in[3];
  const float* Wv    = (const float*)d_in[4];
  const float* bv    = (const float*)d_in[5];
  const float* Wt    = (const float*)d_in[6];
  const float* bt    = (const float*)d_in[7];
  const float* Win   = (const float*)d_in[8];
  const float* bin   = (const float*)d_in[9];
  const float* Wout  = (const float*)d_in[10];
  const float* bout  = (const float*)d_in[11];
  const float* W1    = (const float*)d_in[12];
  const float* b1    = (const float*)d_in[13];
  const float* W2    = (const float*)d_in[14];
  const float* b2    = (const float*)d_in[15];
  const float* gamma = (const float*)d_in[16];
  const float* beta  = (const float*)d_in[17];
  float* out = (float*)d_out;

  char* w = (char*)d_ws;
  const size_t MB = 1ull << 20;
  float* hf    = (float*)(w + 0);         // [0,32)   h f32
  bf16*  hb    = (bf16*) (w + 32 * MB);   // [32,48)  h bf16
  bf16*  qkv   = (bf16*) (w + 48 * MB);   // [48,96)  qkv bf16
  bf16*  vtb   = (bf16*) (w + 96 * MB);   // [96,112) v^T bf16
  bf16*  attnb = (bf16*) (w + 112 * MB);  // [112,128) attn bf16
  float* x1    = (float*)(w + 48 * MB);   // [48,80)  h+attn_out (qkv dead)
  float* h2f   = (float*)(w + 80 * MB);   // [80,112) h2 f32
  bf16*  h2b   = (bf16*) (w + 32 * MB);   // [32,48)  h2 bf16 (hb dead)
  bf16*  ff1   = (bf16*) (w + 112 * MB);  // [112,128) relu(ff1) (attnb dead)
  float* x2    = (float*)(w + 0);         // [0,32)   h2+ff2 (hf dead)
  float* h3    = (float*)(w + 48 * MB);   // [48,80)  h3 (x1 dead)
  bf16*  WinB  = (bf16*) (w + 129 * MB);
  bf16*  WoutB = (bf16*) (w + 135 * MB);
  bf16*  W1B   = (bf16*) (w + 137 * MB);
  bf16*  W2B   = (bf16*) (w + 139 * MB);
  float* part  = (float*)(w + 141 * MB);

  k_f2b<<<3072, 256, 0, stream>>>(Win,  WinB);
  k_f2b<<<1024, 256, 0, stream>>>(Wout, WoutB);
  k_f2b<<<1024, 256, 0, stream>>>(W1,   W1B);
  k_f2b<<<1024, 256, 0, stream>>>(W2,   W2B);

  k_embed<<<Mm, 256, 0, stream>>>(tids, vals, dels, temb, Wv, bv, Wt, bt, hf, hb);

  k_gemm8<false, false, true, false><<<dim3(64, 12), 512, 0, stream>>>(
      hb, WinB, bin, nullptr, nullptr, qkv, 3072, 1024);

  k_vt<<<dim3(128, 16), 256, 0, stream>>>(qkv, vtb);
  k_attn<<<dim3(128, 8), 256, 0, stream>>>(qkv, vtb, attnb);

  k_gemm8<false, true, false, true><<<dim3(64, 4), 512, 0, stream>>>(
      attnb, WoutB, bout, hf, x1, nullptr, 1024, 1024);

  k_ln<true><<<Mm, 256, 0, stream>>>(x1, gamma, beta, h2f, h2b);

  k_gemm8<true, false, true, false><<<dim3(64, 4), 512, 0, stream>>>(
      h2b, W1B, b1, nullptr, nullptr, ff1, 1024, 1024);

  k_gemm8<false, true, false, true><<<dim3(64, 4), 512, 0, stream>>>(
      ff1, W2B, b2, h2f, x2, nullptr, 1024, 1024);

  k_ln<false><<<Mm, 256, 0, stream>>>(x2, gamma, beta, h3, nullptr);

  k_pool_part<<<dim3(8, 16, 4), 256, 0, stream>>>(h3, part);
  k_pool_fin<<<dim3(8, 4), 256, 0, stream>>>(part, out);
}